// Round 6
// baseline (115.807 us; speedup 1.0000x reference)
//
#include <hip/hip_runtime.h>

#define K    5
#define KK   25
#define H    160
#define W    160
#define C    64
#define BS   4
#define HW   (H * W)

#define TX   32          // tile width (pixels)
#define TY   8           // tile height (rows)
#define CPB  16          // channels per block
#define CPW  4           // channels per thread
#define BLK  256

#define FR   (TY + 4)    // fm rows staged (2 halo top + 2 bottom) = 12
#define FS   44          // fm LDS row stride in floats (40 data + 4 pad, 16B aligned)
#define WLS  36          // weight LDS row stride in floats (32 data + 4 pad)

// Block = 32x8 px tile x 16 channels. fm tile (zero-filled halo) + pre-flipped
// weights staged in LDS; all reuse traffic (fm 25x, weights 4x) moves off the
// vector-memory pipe. R1/R5 data fit ~20cyc/VMEM-instr + ~2.3cyc/line on the
// CU memory pipe -> cut wave-VMEM 2725 -> ~890 per CU. Zero-filled halo means
// NO per-tap weight masking (OOB fm is 0.0). No min-waves launch_bounds:
// R3(VGPR40)/R4(VGPR48+spill) proved the cap serializes/spills the batches.
__global__ __launch_bounds__(BLK) void kconv_kernel(
    const float* __restrict__ fm,
    const float* __restrict__ kern,
    const int*  __restrict__ dil,
    float* __restrict__ out)
{
    __shared__ float fmlds[CPB * FR * FS];   // 33792 B
    __shared__ float wlds[KK * TY * WLS];    // 28800 B   (total 62592 <= 64K)

    const int tid   = threadIdx.x;
    const int x0    = blockIdx.x * TX;
    const int y0    = blockIdx.y * TY;
    const int b     = blockIdx.z >> 2;
    const int cg    = blockIdx.z & 3;
    const int cbase = cg * CPB;
    const int d     = dil[0];

    const int lane = tid & 63;
    const int qx   = lane & 7;        // x-quad within tile
    const int ty   = lane >> 3;       // row within tile
    const int c0   = (tid >> 6) * CPW;

    if (d == 1) {
        // ---- stage fm tile: 16 ch x 12 rows x 10 float4 (cols x0-4 .. x0+35), OOB -> 0
        const float* fmb = fm + ((size_t)b * C + cbase) * HW;
        for (int idx = tid; idx < CPB * FR * 10; idx += BLK) {
            const int ch  = idx / (FR * 10);
            const int rem = idx - ch * (FR * 10);
            const int r   = rem / 10;
            const int f4  = rem - r * 10;
            const int gy  = y0 - 2 + r;
            const int gx  = x0 - 4 + 4 * f4;   // multiple of 4: float4 all-in or all-out
            float4 v = make_float4(0.f, 0.f, 0.f, 0.f);
            if (gy >= 0 && gy < H && gx >= 0 && gx < W)
                v = *(const float4*)(fmb + (size_t)ch * HW + (size_t)gy * W + gx);
            *(float4*)&fmlds[(ch * FR + r) * FS + 4 * f4] = v;
        }
        // ---- stage weights, pre-flipped: wlds[t] = kern[b][24-t][tile]
        const float* kb = kern + (size_t)b * KK * HW + (size_t)y0 * W + x0;
        for (int idx = tid; idx < KK * TY * 8; idx += BLK) {
            const int m   = idx / (TY * 8);
            const int rem = idx - m * (TY * 8);
            const int r   = rem / 8;
            const int f4  = rem - r * 8;
            const float4 v = *(const float4*)(kb + (size_t)m * HW + (size_t)r * W + 4 * f4);
            *(float4*)&wlds[((KK - 1 - m) * TY + r) * WLS + 4 * f4] = v;
        }
        __syncthreads();

        float acc[CPW][4];
#pragma unroll
        for (int c = 0; c < CPW; ++c)
#pragma unroll
            for (int p = 0; p < 4; ++p) acc[c][p] = 0.f;

#pragma unroll
        for (int i = 0; i < K; ++i) {
            // weights for this tap row: 5 x b128
            float wr[K][4];
#pragma unroll
            for (int j = 0; j < K; ++j) {
                const float4 wv = *(const float4*)&wlds[((i * K + j) * TY + ty) * WLS + 4 * qx];
                wr[j][0] = wv.x; wr[j][1] = wv.y; wr[j][2] = wv.z; wr[j][3] = wv.w;
            }
            // fm windows: per channel 8 floats, l = 4qx+2 .. 4qx+9 (g = x-2 .. x+5)
            float win[CPW][8];
#pragma unroll
            for (int c = 0; c < CPW; ++c) {
                const int base = ((c0 + c) * FR + ty + i) * FS + 4 * qx + 2;
#pragma unroll
                for (int k = 0; k < 4; ++k) {
                    const float2 t = *(const float2*)&fmlds[base + 2 * k];
                    win[c][2 * k]     = t.x;
                    win[c][2 * k + 1] = t.y;
                }
            }
#pragma unroll
            for (int c = 0; c < CPW; ++c)
#pragma unroll
                for (int j = 0; j < K; ++j)
#pragma unroll
                    for (int p = 0; p < 4; ++p)
                        acc[c][p] = fmaf(wr[j][p], win[c][p + j], acc[c][p]);
        }

        float* ob = out + ((size_t)b * C + cbase + c0) * HW + (size_t)(y0 + ty) * W + x0 + 4 * qx;
#pragma unroll
        for (int c = 0; c < CPW; ++c) {
            const float4 o = {acc[c][0], acc[c][1], acc[c][2], acc[c][3]};
            *(float4*)(ob + (size_t)c * HW) = o;
        }
    } else {
        // Generic-dilation fallback (never taken in this bench; d==1 there).
        const int x = x0 + 4 * qx;
        const int y = y0 + ty;
        const float* fb  = fm  + ((size_t)b * C + cbase + c0) * HW;
        float*       ob  = out + ((size_t)b * C + cbase + c0) * HW + (size_t)y * W + x;
        const float* kbp = kern + (size_t)b * KK * HW + (size_t)y * W + x;
#pragma unroll 1
        for (int p = 0; p < 4; ++p) {
            const int xx = x + p;
            float wgt[KK];
            int   offs[KK];
#pragma unroll 1
            for (int i = 0; i < K; ++i) {
                const int  yy  = y + (i - 2) * d;
                const bool yok = (yy >= 0) && (yy < H);
                const int  yc  = min(max(yy, 0), H - 1);
#pragma unroll 1
                for (int j = 0; j < K; ++j) {
                    const int  xc  = xx + (j - 2) * d;
                    const bool ok  = yok && (xc >= 0) && (xc < W);
                    const int  xcc = min(max(xc, 0), W - 1);
                    const int  t   = i * K + j;
                    wgt[t]  = ok ? kbp[(size_t)(KK - 1 - t) * HW + p] : 0.f;
                    offs[t] = yc * W + xcc;
                }
            }
#pragma unroll 1
            for (int c = 0; c < CPW; ++c) {
                const float* fc = fb + (size_t)c * HW;
                float a2 = 0.f;
#pragma unroll 1
                for (int t = 0; t < KK; ++t) a2 = fmaf(wgt[t], fc[offs[t]], a2);
                ob[(size_t)c * HW + p] = a2;
            }
        }
    }
}

extern "C" void kernel_launch(void* const* d_in, const int* in_sizes, int n_in,
                              void* d_out, int out_size, void* d_ws, size_t ws_size,
                              hipStream_t stream)
{
    const float* fm   = (const float*)d_in[0];
    const float* kern = (const float*)d_in[1];
    const int*   dil  = (const int*)d_in[2];
    float*       out  = (float*)d_out;

    dim3 grid(W / TX, H / TY, BS * (C / CPB));   // 5 x 20 x 16 = 1600 blocks
    kconv_kernel<<<grid, dim3(BLK), 0, stream>>>(fm, kern, dil, out);
}

// Round 7
// 103.517 us; speedup vs baseline: 1.1187x; 1.1187x over previous
//
#include <hip/hip_runtime.h>

#define K    5
#define KK   25
#define H    160
#define W    160
#define C    64
#define BS   4
#define HW   (H * W)

#define TX   32          // tile width (pixels)
#define TY   8           // tile height (rows)
#define CPB  16          // channels per block
#define CPW  4           // channels per thread
#define BLK  256

#define FR   (TY + 4)    // fm rows staged (2 halo top + 2 bottom) = 12
#define FS   46          // fm LDS row stride: 46*4=184B -> b64 window reads hit
                         // all 32 banks at depth 4 (= b64 minimum, conflict-free;
                         // R6's FS=44 gave 16 banks x depth 8 = 5.4M conflict cyc)

// Block = 32x8 px tile x 16 ch. ONLY fm staged in LDS (25x reuse); weights come
// straight from global as float4 (4x reuse -> L1's job; putting them in LDS cost
// 28.8KB and halved occupancy in R6). LDS 34.5KB -> 4 blocks/CU so staging of
// one block overlaps compute of another. Zero-filled halo -> no weight masking.
// No min-waves launch_bounds: R3/R4 proved the VGPR cap serializes/spills.
__global__ __launch_bounds__(BLK) void kconv_kernel(
    const float* __restrict__ fm,
    const float* __restrict__ kern,
    const int*  __restrict__ dil,
    float* __restrict__ out)
{
    __shared__ float fmlds[CPB * FR * FS];   // 35328 B

    const int tid   = threadIdx.x;
    const int x0    = blockIdx.x * TX;
    const int y0    = blockIdx.y * TY;
    const int b     = blockIdx.z >> 2;
    const int cg    = blockIdx.z & 3;
    const int cbase = cg * CPB;
    const int d     = dil[0];

    const int lane = tid & 63;
    const int qx   = lane & 7;        // x-quad within tile row
    const int ty   = lane >> 3;       // row within tile
    const int c0   = (tid >> 6) * CPW;

    const int x = x0 + 4 * qx;
    const int y = y0 + ty;
    const float* kb = kern + (size_t)b * KK * HW + (size_t)y * W + x;

    if (d == 1) {
        // ---- stage fm tile: 16 ch x 12 rows x 10 float4 (cols x0-4..x0+35), OOB -> 0
        const float* fmb = fm + ((size_t)b * C + cbase) * HW;
        for (int idx = tid; idx < CPB * FR * 10; idx += BLK) {   // 1920 float4
            const int ch  = idx / (FR * 10);
            const int rem = idx - ch * (FR * 10);
            const int r   = rem / 10;
            const int f4  = rem - r * 10;
            const int gy  = y0 - 2 + r;
            const int gx  = x0 - 4 + 4 * f4;   // mult of 4: float4 all-in or all-out
            float4 v = make_float4(0.f, 0.f, 0.f, 0.f);
            if (gy >= 0 && gy < H && gx >= 0 && gx < W)
                v = *(const float4*)(fmb + (size_t)ch * HW + (size_t)gy * W + gx);
            float* dst = &fmlds[(ch * FR + r) * FS + 4 * f4];    // 8B-aligned (FS even)
            *(float2*)dst       = make_float2(v.x, v.y);
            *(float2*)(dst + 2) = make_float2(v.z, v.w);
        }
        __syncthreads();

        float acc[CPW][4];
#pragma unroll
        for (int c = 0; c < CPW; ++c)
#pragma unroll
            for (int p = 0; p < 4; ++p) acc[c][p] = 0.f;

#pragma unroll
        for (int i = 0; i < K; ++i) {
            // weights for this tap row, straight from global (flipped); no masking
            // needed: OOB fm positions are zero in LDS.
            float wr[K][4];
#pragma unroll
            for (int j = 0; j < K; ++j) {
                const int t = i * K + j;
                const float4 wv = *(const float4*)(kb + (size_t)(KK - 1 - t) * HW);
                wr[j][0] = wv.x; wr[j][1] = wv.y; wr[j][2] = wv.z; wr[j][3] = wv.w;
            }
            // fm windows from LDS: per channel 8 floats (cols x-2..x+5), 4x b64
            float win[CPW][8];
#pragma unroll
            for (int c = 0; c < CPW; ++c) {
                const int base = ((c0 + c) * FR + ty + i) * FS + 4 * qx + 2;
#pragma unroll
                for (int k = 0; k < 4; ++k) {
                    const float2 t2 = *(const float2*)&fmlds[base + 2 * k];
                    win[c][2 * k]     = t2.x;
                    win[c][2 * k + 1] = t2.y;
                }
            }
#pragma unroll
            for (int c = 0; c < CPW; ++c)
#pragma unroll
                for (int j = 0; j < K; ++j)
#pragma unroll
                    for (int p = 0; p < 4; ++p)
                        acc[c][p] = fmaf(wr[j][p], win[c][p + j], acc[c][p]);
        }

        float* ob = out + ((size_t)b * C + cbase + c0) * HW + (size_t)y * W + x;
#pragma unroll
        for (int c = 0; c < CPW; ++c) {
            const float4 o = {acc[c][0], acc[c][1], acc[c][2], acc[c][3]};
            *(float4*)(ob + (size_t)c * HW) = o;
        }
    } else {
        // Generic-dilation fallback (never taken in this bench; d==1 there).
        const float* fb = fm  + ((size_t)b * C + cbase + c0) * HW;
        float*       ob = out + ((size_t)b * C + cbase + c0) * HW + (size_t)y * W + x;
#pragma unroll 1
        for (int p = 0; p < 4; ++p) {
            const int xx = x + p;
            float wgt[KK];
            int   offs[KK];
#pragma unroll 1
            for (int i = 0; i < K; ++i) {
                const int  yy  = y + (i - 2) * d;
                const bool yok = (yy >= 0) && (yy < H);
                const int  yc  = min(max(yy, 0), H - 1);
#pragma unroll 1
                for (int j = 0; j < K; ++j) {
                    const int  xc  = xx + (j - 2) * d;
                    const bool ok  = yok && (xc >= 0) && (xc < W);
                    const int  xcc = min(max(xc, 0), W - 1);
                    const int  t   = i * K + j;
                    wgt[t]  = ok ? kb[(size_t)(KK - 1 - t) * HW + p] : 0.f;
                    offs[t] = yc * W + xcc;
                }
            }
#pragma unroll 1
            for (int c = 0; c < CPW; ++c) {
                const float* fc = fb + (size_t)c * HW;
                float a2 = 0.f;
#pragma unroll 1
                for (int t = 0; t < KK; ++t) a2 = fmaf(wgt[t], fc[offs[t]], a2);
                ob[(size_t)c * HW + p] = a2;
            }
        }
    }
}

extern "C" void kernel_launch(void* const* d_in, const int* in_sizes, int n_in,
                              void* d_out, int out_size, void* d_ws, size_t ws_size,
                              hipStream_t stream)
{
    const float* fm   = (const float*)d_in[0];
    const float* kern = (const float*)d_in[1];
    const int*   dil  = (const int*)d_in[2];
    float*       out  = (float*)d_out;

    dim3 grid(W / TX, H / TY, BS * (C / CPB));   // 5 x 20 x 16 = 1600 blocks
    kconv_kernel<<<grid, dim3(BLK), 0, stream>>>(fm, kern, dil, out);
}

// Round 8
// 103.352 us; speedup vs baseline: 1.1205x; 1.0016x over previous
//
#include <hip/hip_runtime.h>

#define K    5
#define KK   25
#define H    160
#define W    160
#define C    64
#define BS   4
#define HW   (H * W)

#define TX   32          // tile width (pixels)
#define TY   8           // tile height (rows)
#define CPB  16          // channels per block
#define CPW  4           // channels per thread
#define BLK  256

#define FR   (TY + 4)    // fm rows staged (2 halo top + 2 bottom) = 12
#define FS   46          // fm LDS row stride: conflict-free b64 window reads (R7)

// R7 + software-pipelined weight loads. R2/R5/R6/R7 all plateau ~36-45us with
// every throughput pipe <35% busy -> the wall is EXPOSED VMEM LATENCY: R7's
// VGPR=88 shows the compiler issued the 25 per-thread weight loads in per-row
// dribbles, eating ~300cyc L2 latency 5x per wave. Fix: double-buffer tap-row
// weights in registers — row i+1's 5 float4 globals issue before row i's
// LDS reads + 80 FMAs (~400cyc of cover); row 0's loads overlap the fm
// staging + barrier. fm stays in LDS (35KB, 4 blocks/CU, FS=46 pad).
// No min-waves launch_bounds: R3/R4 proved the VGPR cap serializes/spills.
__global__ __launch_bounds__(BLK) void kconv_kernel(
    const float* __restrict__ fm,
    const float* __restrict__ kern,
    const int*  __restrict__ dil,
    float* __restrict__ out)
{
    __shared__ float fmlds[CPB * FR * FS];   // 35328 B

    const int tid   = threadIdx.x;
    const int x0    = blockIdx.x * TX;
    const int y0    = blockIdx.y * TY;
    const int b     = blockIdx.z >> 2;
    const int cg    = blockIdx.z & 3;
    const int cbase = cg * CPB;
    const int d     = dil[0];

    const int lane = tid & 63;
    const int qx   = lane & 7;        // x-quad within tile row
    const int ty   = lane >> 3;       // row within tile
    const int c0   = (tid >> 6) * CPW;

    const int x = x0 + 4 * qx;
    const int y = y0 + ty;
    const float* kb = kern + (size_t)b * KK * HW + (size_t)y * W + x;

    if (d == 1) {
        // -- prologue: issue tap-row 0 weight loads (flipped) BEFORE staging --
        float4 wbuf[2][K];
#pragma unroll
        for (int j = 0; j < K; ++j)
            wbuf[0][j] = *(const float4*)(kb + (size_t)(KK - 1 - j) * HW);

        // ---- stage fm tile: 16 ch x 12 rows x 10 float4 (cols x0-4..x0+35), OOB -> 0
        const float* fmb = fm + ((size_t)b * C + cbase) * HW;
        for (int idx = tid; idx < CPB * FR * 10; idx += BLK) {   // 1920 float4
            const int ch  = idx / (FR * 10);
            const int rem = idx - ch * (FR * 10);
            const int r   = rem / 10;
            const int f4  = rem - r * 10;
            const int gy  = y0 - 2 + r;
            const int gx  = x0 - 4 + 4 * f4;   // mult of 4: float4 all-in or all-out
            float4 v = make_float4(0.f, 0.f, 0.f, 0.f);
            if (gy >= 0 && gy < H && gx >= 0 && gx < W)
                v = *(const float4*)(fmb + (size_t)ch * HW + (size_t)gy * W + gx);
            float* dst = &fmlds[(ch * FR + r) * FS + 4 * f4];    // 8B-aligned (FS even)
            *(float2*)dst       = make_float2(v.x, v.y);
            *(float2*)(dst + 2) = make_float2(v.z, v.w);
        }
        __syncthreads();

        float acc[CPW][4];
#pragma unroll
        for (int c = 0; c < CPW; ++c)
#pragma unroll
            for (int p = 0; p < 4; ++p) acc[c][p] = 0.f;

#pragma unroll
        for (int i = 0; i < K; ++i) {
            // issue NEXT tap-row's weight loads first (long-latency, independent)
            if (i + 1 < K) {
#pragma unroll
                for (int j = 0; j < K; ++j)
                    wbuf[(i + 1) & 1][j] =
                        *(const float4*)(kb + (size_t)(KK - 1 - ((i + 1) * K + j)) * HW);
            }
            // fm windows from LDS: per channel 8 floats (cols x-2..x+5), 4x b64
            float win[CPW][8];
#pragma unroll
            for (int c = 0; c < CPW; ++c) {
                const int base = ((c0 + c) * FR + ty + i) * FS + 4 * qx + 2;
#pragma unroll
                for (int k = 0; k < 4; ++k) {
                    const float2 t2 = *(const float2*)&fmlds[base + 2 * k];
                    win[c][2 * k]     = t2.x;
                    win[c][2 * k + 1] = t2.y;
                }
            }
            // FMAs for row i using the current weight buffer (no masking: halo is 0)
            const float4* wv = wbuf[i & 1];
#pragma unroll
            for (int c = 0; c < CPW; ++c)
#pragma unroll
                for (int j = 0; j < K; ++j) {
                    const float wf[4] = {wv[j].x, wv[j].y, wv[j].z, wv[j].w};
#pragma unroll
                    for (int p = 0; p < 4; ++p)
                        acc[c][p] = fmaf(wf[p], win[c][p + j], acc[c][p]);
                }
        }

        float* ob = out + ((size_t)b * C + cbase + c0) * HW + (size_t)y * W + x;
#pragma unroll
        for (int c = 0; c < CPW; ++c) {
            const float4 o = {acc[c][0], acc[c][1], acc[c][2], acc[c][3]};
            *(float4*)(ob + (size_t)c * HW) = o;
        }
    } else {
        // Generic-dilation fallback (never taken in this bench; d==1 there).
        const float* fb = fm  + ((size_t)b * C + cbase + c0) * HW;
        float*       ob = out + ((size_t)b * C + cbase + c0) * HW + (size_t)y * W + x;
#pragma unroll 1
        for (int p = 0; p < 4; ++p) {
            const int xx = x + p;
            float wgt[KK];
            int   offs[KK];
#pragma unroll 1
            for (int i = 0; i < K; ++i) {
                const int  yy  = y + (i - 2) * d;
                const bool yok = (yy >= 0) && (yy < H);
                const int  yc  = min(max(yy, 0), H - 1);
#pragma unroll 1
                for (int j = 0; j < K; ++j) {
                    const int  xc  = xx + (j - 2) * d;
                    const bool ok  = yok && (xc >= 0) && (xc < W);
                    const int  xcc = min(max(xc, 0), W - 1);
                    const int  t   = i * K + j;
                    wgt[t]  = ok ? kb[(size_t)(KK - 1 - t) * HW + p] : 0.f;
                    offs[t] = yc * W + xcc;
                }
            }
#pragma unroll 1
            for (int c = 0; c < CPW; ++c) {
                const float* fc = fb + (size_t)c * HW;
                float a2 = 0.f;
#pragma unroll 1
                for (int t = 0; t < KK; ++t) a2 = fmaf(wgt[t], fc[offs[t]], a2);
                ob[(size_t)c * HW + p] = a2;
            }
        }
    }
}

extern "C" void kernel_launch(void* const* d_in, const int* in_sizes, int n_in,
                              void* d_out, int out_size, void* d_ws, size_t ws_size,
                              hipStream_t stream)
{
    const float* fm   = (const float*)d_in[0];
    const float* kern = (const float*)d_in[1];
    const int*   dil  = (const int*)d_in[2];
    float*       out  = (float*)d_out;

    dim3 grid(W / TX, H / TY, BS * (C / CPB));   // 5 x 20 x 16 = 1600 blocks
    kconv_kernel<<<grid, dim3(BLK), 0, stream>>>(fm, kern, dil, out);
}

// Round 9
// 96.502 us; speedup vs baseline: 1.2000x; 1.0710x over previous
//
#include <hip/hip_runtime.h>

#define K    5
#define KK   25
#define H    160
#define W    160
#define C    64
#define BS   4
#define HW   (H * W)

#define TX   32          // tile width (pixels)
#define TY   8           // tile height (rows)
#define CPB  8           // channels per block (R9: 16->8 to halve LDS)
#define CPW  2           // channels per thread
#define BLK  256

#define FR   (TY + 4)    // fm rows staged (2 halo top + 2 bottom) = 12
#define FS   46          // fm LDS row stride: conflict-free b64 window reads (R7)

// R9 = R7 with CPB halved. R7/R8 plateau at ~36us with all pipes <35% busy and
// only 4 resident blocks (35KB LDS) = 16 waves/CU: the staging barrier phase-
// locks each block and there is not enough cross-block TLP to cover it. This
// version: 17.7KB LDS -> ~8 resident blocks, 28-32 waves/CU, grid 3200 blocks
// (12.5/CU) so staging of some blocks always overlaps compute of others.
// cg folded into grid.x so the 8 z-sibling blocks of a spatial tile dispatch
// consecutively (same XCD L2) -> weight re-reads stay out of HBM.
// No min-waves launch_bounds (R3/R4: cap => serialize/spill); no weight
// register prefetch (R8: neutral, costs 20 VGPR of residency).
__global__ __launch_bounds__(BLK) void kconv_kernel(
    const float* __restrict__ fm,
    const float* __restrict__ kern,
    const int*  __restrict__ dil,
    float* __restrict__ out)
{
    __shared__ float fmlds[CPB * FR * FS];   // 17664 B

    const int tid   = threadIdx.x;
    const int gx    = blockIdx.x;
    const int x0    = (gx >> 3) * TX;        // 5 spatial x-tiles
    const int cg    = gx & 7;                // 8 channel groups, dispatch-adjacent
    const int y0    = blockIdx.y * TY;
    const int b     = blockIdx.z;
    const int cbase = cg * CPB;
    const int d     = dil[0];

    const int lane = tid & 63;
    const int qx   = lane & 7;        // x-quad within tile row
    const int ty   = lane >> 3;       // row within tile
    const int c0   = (tid >> 6) * CPW;   // {0,2,4,6}

    const int x = x0 + 4 * qx;
    const int y = y0 + ty;
    const float* kb = kern + (size_t)b * KK * HW + (size_t)y * W + x;

    if (d == 1) {
        // ---- stage fm tile: 8 ch x 12 rows x 10 float4 (cols x0-4..x0+35), OOB -> 0
        const float* fmb = fm + ((size_t)b * C + cbase) * HW;
        for (int idx = tid; idx < CPB * FR * 10; idx += BLK) {   // 960 float4
            const int ch  = idx / (FR * 10);
            const int rem = idx - ch * (FR * 10);
            const int r   = rem / 10;
            const int f4  = rem - r * 10;
            const int gy  = y0 - 2 + r;
            const int gxc = x0 - 4 + 4 * f4;   // mult of 4: float4 all-in or all-out
            float4 v = make_float4(0.f, 0.f, 0.f, 0.f);
            if (gy >= 0 && gy < H && gxc >= 0 && gxc < W)
                v = *(const float4*)(fmb + (size_t)ch * HW + (size_t)gy * W + gxc);
            float* dst = &fmlds[(ch * FR + r) * FS + 4 * f4];    // 8B-aligned (FS even)
            *(float2*)dst       = make_float2(v.x, v.y);
            *(float2*)(dst + 2) = make_float2(v.z, v.w);
        }
        __syncthreads();

        float acc[CPW][4];
#pragma unroll
        for (int c = 0; c < CPW; ++c)
#pragma unroll
            for (int p = 0; p < 4; ++p) acc[c][p] = 0.f;

#pragma unroll
        for (int i = 0; i < K; ++i) {
            // weights for this tap row, straight from global (flipped); no masking
            // needed: OOB fm positions are zero in LDS.
            float wr[K][4];
#pragma unroll
            for (int j = 0; j < K; ++j) {
                const int t = i * K + j;
                const float4 wv = *(const float4*)(kb + (size_t)(KK - 1 - t) * HW);
                wr[j][0] = wv.x; wr[j][1] = wv.y; wr[j][2] = wv.z; wr[j][3] = wv.w;
            }
            // fm windows from LDS: per channel 8 floats (cols x-2..x+5), 4x b64
            float win[CPW][8];
#pragma unroll
            for (int c = 0; c < CPW; ++c) {
                const int base = ((c0 + c) * FR + ty + i) * FS + 4 * qx + 2;
#pragma unroll
                for (int k = 0; k < 4; ++k) {
                    const float2 t2 = *(const float2*)&fmlds[base + 2 * k];
                    win[c][2 * k]     = t2.x;
                    win[c][2 * k + 1] = t2.y;
                }
            }
#pragma unroll
            for (int c = 0; c < CPW; ++c)
#pragma unroll
                for (int j = 0; j < K; ++j)
#pragma unroll
                    for (int p = 0; p < 4; ++p)
                        acc[c][p] = fmaf(wr[j][p], win[c][p + j], acc[c][p]);
        }

        float* ob = out + ((size_t)b * C + cbase + c0) * HW + (size_t)y * W + x;
#pragma unroll
        for (int c = 0; c < CPW; ++c) {
            const float4 o = {acc[c][0], acc[c][1], acc[c][2], acc[c][3]};
            *(float4*)(ob + (size_t)c * HW) = o;
        }
    } else {
        // Generic-dilation fallback (never taken in this bench; d==1 there).
        const float* fb = fm  + ((size_t)b * C + cbase + c0) * HW;
        float*       ob = out + ((size_t)b * C + cbase + c0) * HW + (size_t)y * W + x;
#pragma unroll 1
        for (int p = 0; p < 4; ++p) {
            const int xx = x + p;
            float wgt[KK];
            int   offs[KK];
#pragma unroll 1
            for (int i = 0; i < K; ++i) {
                const int  yy  = y + (i - 2) * d;
                const bool yok = (yy >= 0) && (yy < H);
                const int  yc  = min(max(yy, 0), H - 1);
#pragma unroll 1
                for (int j = 0; j < K; ++j) {
                    const int  xc  = xx + (j - 2) * d;
                    const bool ok  = yok && (xc >= 0) && (xc < W);
                    const int  xcc = min(max(xc, 0), W - 1);
                    const int  t   = i * K + j;
                    wgt[t]  = ok ? kb[(size_t)(KK - 1 - t) * HW + p] : 0.f;
                    offs[t] = yc * W + xcc;
                }
            }
#pragma unroll 1
            for (int c = 0; c < CPW; ++c) {
                const float* fc = fb + (size_t)c * HW;
                float a2 = 0.f;
#pragma unroll 1
                for (int t = 0; t < KK; ++t) a2 = fmaf(wgt[t], fc[offs[t]], a2);
                ob[(size_t)c * HW + p] = a2;
            }
        }
    }
}

extern "C" void kernel_launch(void* const* d_in, const int* in_sizes, int n_in,
                              void* d_out, int out_size, void* d_ws, size_t ws_size,
                              hipStream_t stream)
{
    const float* fm   = (const float*)d_in[0];
    const float* kern = (const float*)d_in[1];
    const int*   dil  = (const int*)d_in[2];
    float*       out  = (float*)d_out;

    dim3 grid(8 * (W / TX), H / TY, BS);   // 40 x 20 x 4 = 3200 blocks
    kconv_kernel<<<grid, dim3(BLK), 0, stream>>>(fm, kern, dil, out);
}